// Round 9
// baseline (313.377 us; speedup 1.0000x reference)
//
#include <hip/hip_runtime.h>

#define BATCH 262144
#define EMB 300
#define NBLK 4096      // 4096 blocks x 4 waves x 16 pairs = 262144 pairs
#define OFF2 152       // pass1: float4 idx [0,38) = dims 0..151 ; pass2: 37 float4 = dims 152..299

// ---- pass 1: partial dot over dims [0,152) ; working set 2 x ~61 MB fits L3 ----
__global__ __launch_bounds__(256) void glove_pass1(
    const int*   __restrict__ center,
    const int*   __restrict__ outside,
    const float* __restrict__ cemb,
    const float* __restrict__ oemb,
    float*       __restrict__ partial)
{
    const int tid  = threadIdx.x;
    const int warp = tid >> 6;
    const int lane = tid & 63;
    const int l4   = lane & 3;
    const int pg   = lane >> 2;
    const int p    = (blockIdx.x * 4 + warp) * 16 + pg;

    const int ci = center[p];
    const int oi = outside[p];
    const float4* __restrict__ A = (const float4*)(cemb + (long)ci * EMB);
    const float4* __restrict__ B = (const float4*)(oemb + (long)oi * EMB);

    float acc = 0.0f;
    #pragma unroll
    for (int k = 0; k < 9; ++k) {          // float4 idx 0..35
        float4 a = A[l4 + 4 * k];
        float4 b = B[l4 + 4 * k];
        acc += a.x * b.x + a.y * b.y + a.z * b.z + a.w * b.w;
    }
    if (l4 < 2) {                          // idx 36,37
        float4 a = A[36 + l4];
        float4 b = B[36 + l4];
        acc += a.x * b.x + a.y * b.y + a.z * b.z + a.w * b.w;
    }

    acc += __shfl_xor(acc, 1);
    acc += __shfl_xor(acc, 2);
    if (l4 == 0) partial[p] = acc;         // 16 consecutive floats per wave
}

// ---- pass 2: dims [152,300) + bias/cooc/weight + squared loss ----
__global__ __launch_bounds__(256) void glove_pass2(
    const int*   __restrict__ center,
    const int*   __restrict__ outside,
    const float* __restrict__ coocs,
    const float* __restrict__ weighting,
    const float* __restrict__ cemb,
    const float* __restrict__ oemb,
    const float* __restrict__ cbias,
    const float* __restrict__ obias,
    const float* __restrict__ partial,
    float*       __restrict__ block_sums)
{
    const int tid  = threadIdx.x;
    const int warp = tid >> 6;
    const int lane = tid & 63;
    const int l4   = lane & 3;
    const int pg   = lane >> 2;
    const int p    = (blockIdx.x * 4 + warp) * 16 + pg;

    const int ci = center[p];
    const int oi = outside[p];
    // byte offset ci*1200 + 608 : 16B-aligned (608 = 38*16)
    const float4* __restrict__ A = (const float4*)(cemb + (long)ci * EMB + OFF2);
    const float4* __restrict__ B = (const float4*)(oemb + (long)oi * EMB + OFF2);

    const float cc = coocs[p];
    const float wt = weighting[p];
    const float cb = cbias[ci];
    const float ob = obias[oi];
    const float pp = partial[p];

    float acc = 0.0f;
    #pragma unroll
    for (int k = 0; k < 9; ++k) {          // float4 idx 0..35 (of 37)
        float4 a = A[l4 + 4 * k];
        float4 b = B[l4 + 4 * k];
        acc += a.x * b.x + a.y * b.y + a.z * b.z + a.w * b.w;
    }
    if (l4 == 0) {                         // idx 36
        float4 a = A[36];
        float4 b = B[36];
        acc += a.x * b.x + a.y * b.y + a.z * b.z + a.w * b.w;
    }

    acc += __shfl_xor(acc, 1);
    acc += __shfl_xor(acc, 2);

    float local = 0.0f;
    if (l4 == 0) {
        const float e = acc + pp + cb + ob - cc;
        local = wt * e * e;
    }
    #pragma unroll
    for (int off = 32; off > 0; off >>= 1)
        local += __shfl_down(local, off, 64);

    __shared__ float smem[4];
    if (lane == 0) smem[warp] = local;
    __syncthreads();
    if (tid == 0)
        block_sums[blockIdx.x] = smem[0] + smem[1] + smem[2] + smem[3];
}

__global__ __launch_bounds__(1024) void glove_reduce(
    const float* __restrict__ part, float* __restrict__ out)
{
    const int t = threadIdx.x;
    float4 v = ((const float4*)part)[t];          // 1024 x 4 = 4096 partials
    float s = v.x + v.y + v.z + v.w;
    #pragma unroll
    for (int off = 32; off > 0; off >>= 1)
        s += __shfl_down(s, off, 64);
    __shared__ float sm[16];
    if ((t & 63) == 0) sm[t >> 6] = s;
    __syncthreads();
    if (t < 16) {
        float x = sm[t];
        #pragma unroll
        for (int off = 8; off > 0; off >>= 1)
            x += __shfl_down(x, off, 16);
        if (t == 0) out[0] = x;
    }
}

extern "C" void kernel_launch(void* const* d_in, const int* in_sizes, int n_in,
                              void* d_out, int out_size, void* d_ws, size_t ws_size,
                              hipStream_t stream) {
    const int*   center    = (const int*)  d_in[0];
    const int*   outside   = (const int*)  d_in[1];
    const float* coocs     = (const float*)d_in[2];
    const float* weighting = (const float*)d_in[3];
    const float* cemb      = (const float*)d_in[4];
    const float* oemb      = (const float*)d_in[5];
    const float* cbias     = (const float*)d_in[6];
    const float* obias     = (const float*)d_in[7];
    float* out = (float*)d_out;

    char* ws = (char*)d_ws;
    float* partial    = (float*)ws;                          // BATCH floats = 1 MB
    float* block_sums = (float*)(ws + (size_t)BATCH * 4);    // NBLK floats = 16 KB

    glove_pass1<<<NBLK, 256, 0, stream>>>(center, outside, cemb, oemb, partial);
    glove_pass2<<<NBLK, 256, 0, stream>>>(center, outside, coocs, weighting,
                                          cemb, oemb, cbias, obias, partial,
                                          block_sums);
    glove_reduce<<<1, 1024, 0, stream>>>(block_sums, out);
}